// Round 6
// baseline (248.408 us; speedup 1.0000x reference)
//
#include <hip/hip_runtime.h>
#include <hip/hip_bf16.h>
#include <cstdint>
#include <cmath>

#define T_TOK 8192
#define HD 1024
#define ID 512
#define NE 8
#define BM 128
#define BK 64
#define MAXMT (T_TOK / BM)   // 64

#define GU_BN 128
#define GU_SPACE (MAXMT * (ID / GU_BN))   // 64*4 = 256 per-expert tile space; active ~32
#define GU_BPE 32
#define GU_GRID (NE * GU_BPE)             // 256
#define DN_BN 256
#define DN_SPACE (MAXMT * (HD / DN_BN))   // 256; active ~32
#define DN_BPE 32
#define DN_GRID (NE * DN_BPE)             // 256

typedef __attribute__((ext_vector_type(8))) short short8;
typedef __attribute__((ext_vector_type(4))) float f32x4;

__device__ __forceinline__ unsigned short f2bf(float f) {
  union { float f; unsigned int u; } v; v.f = f;
  unsigned int u = v.u;
  u += 0x7fffu + ((u >> 16) & 1u);   // RNE
  return (unsigned short)(u >> 16);
}

#if __has_builtin(__builtin_amdgcn_global_load_lds)
#define HAVE_GLDS 1
#endif

// Global->LDS 16B/lane. LDS dest = wave-uniform base + lane*16.
__device__ __forceinline__ void stage16(const ushort* __restrict__ g,
                                        ushort* lds_wave_base, int lane) {
#ifdef HAVE_GLDS
  __builtin_amdgcn_global_load_lds((const __attribute__((address_space(1))) void*)g,
                                   (__attribute__((address_space(3))) void*)lds_wave_base,
                                   16, 0, 0);
#else
  *(uint4*)(lds_wave_base + (size_t)lane * 8) = *(const uint4*)g;
#endif
}

// BK=64: one glds instr stages 8 rows x 128B. Lane l -> row rl=l>>3, dest slot c=l&7.
// Slot c holds global colgroup c ^ (rl&7) (XOR swizzle; verified 0 bank conflicts).
__device__ __forceinline__ void stageChunk(const ushort* __restrict__ rowbase, size_t ld,
                                           int k0, ushort* ldsChunk, int lane) {
  int rl = lane >> 3;
  int gc = (lane & 7) ^ (rl & 7);
  stage16(rowbase + (size_t)rl * ld + k0 + gc * 8, ldsChunk, lane);
}

// Read 8-elem bf16 frag at (row r, global colgroup g), undoing swizzle.
__device__ __forceinline__ short8 fragRd(const ushort* buf, int r, int g) {
  int slot = g ^ (r & 7);
  return *(const short8*)&buf[r * BK + slot * 8];
}

// ---------------- router: logits (fp64 acc), argmax, sigmoid ----------------
__global__ __launch_bounds__(256) void k_router(const float* __restrict__ x,
                                                const float* __restrict__ gw,
                                                int* __restrict__ sel,
                                                float* __restrict__ rw) {
  int wv = threadIdx.x >> 6, lane = threadIdx.x & 63;
  int t = blockIdx.x * 4 + wv;
  const float4* xr = (const float4*)(x + (size_t)t * HD);
  double acc[NE];
#pragma unroll
  for (int e = 0; e < NE; e++) acc[e] = 0.0;
#pragma unroll
  for (int j = 0; j < 4; j++) {
    float4 xv = xr[lane + 64 * j];
#pragma unroll
    for (int e = 0; e < NE; e++) {
      float4 wv4 = ((const float4*)(gw + e * HD))[lane + 64 * j];
      acc[e] += (double)xv.x * wv4.x + (double)xv.y * wv4.y +
                (double)xv.z * wv4.z + (double)xv.w * wv4.w;
    }
  }
#pragma unroll
  for (int e = 0; e < NE; e++)
    for (int off = 32; off >= 1; off >>= 1)
      acc[e] += __shfl_xor(acc[e], off);
  if (lane == 0) {
    double best = acc[0]; int bi = 0;
#pragma unroll
    for (int e = 1; e < NE; e++) if (acc[e] > best) { best = acc[e]; bi = e; }
    sel[t] = bi;
    rw[t] = (float)(1.0 / (1.0 + exp(-best)));
  }
}

// ---------------- single-block count + scan + permutation (no atomics) ----------
__global__ __launch_bounds__(1024) void k_scan(const int* __restrict__ sel,
                                               int* __restrict__ cnt,
                                               int* __restrict__ perm) {
  __shared__ int wbase[NE][16];
  __shared__ int off[NE];
  int tid = threadIdx.x;
  int wv = tid >> 6, lane = tid & 63;

  int4 s0 = ((const int4*)sel)[tid * 2];
  int4 s1 = ((const int4*)sel)[tid * 2 + 1];
  int sl[8] = {s0.x, s0.y, s0.z, s0.w, s1.x, s1.y, s1.z, s1.w};

  int c[NE];
#pragma unroll
  for (int e = 0; e < NE; e++) c[e] = 0;
#pragma unroll
  for (int i = 0; i < 8; i++)
#pragma unroll
    for (int e = 0; e < NE; e++) c[e] += (sl[i] == e) ? 1 : 0;

  int pre[NE];
#pragma unroll
  for (int e = 0; e < NE; e++) {
    int v = c[e];
#pragma unroll
    for (int d = 1; d < 64; d <<= 1) {
      int u = __shfl_up(v, d);
      if (lane >= d) v += u;
    }
    pre[e] = v - c[e];
    if (lane == 63) wbase[e][wv] = v;
  }
  __syncthreads();
  if (tid < NE) {
    int a = 0;
#pragma unroll
    for (int w = 0; w < 16; w++) { int v = wbase[tid][w]; wbase[tid][w] = a; a += v; }
    cnt[tid] = a;
    off[tid] = a;
  }
  __syncthreads();
  if (tid == 0) {
    int a = 0;
#pragma unroll
    for (int e = 0; e < NE; e++) { int v = off[e]; off[e] = a; a += v; }
  }
  __syncthreads();
  int t0 = tid * 8;
#pragma unroll
  for (int i = 0; i < 8; i++) {
    int e = sl[i];
    int r = 0;
#pragma unroll
    for (int q = 0; q < NE; q++)
      if (q == e) { r = off[q] + wbase[q][wv] + pre[q]; pre[q]++; }
    perm[r] = t0 + i;
  }
}

// gather + routing-weight scale + fp32->bf16
__global__ __launch_bounds__(256) void k_gather(const float* __restrict__ x,
                                                const float* __restrict__ rw,
                                                const int* __restrict__ perm,
                                                ushort* __restrict__ xs) {
  int p = blockIdx.x;
  int t = perm[p];
  float s = rw[t];
  const float4* src = (const float4*)(x + (size_t)t * HD);
  ushort4* dst = (ushort4*)(xs + (size_t)p * HD);
  float4 v = src[threadIdx.x];
  ushort4 o;
  o.x = f2bf(v.x * s); o.y = f2bf(v.y * s); o.z = f2bf(v.z * s); o.w = f2bf(v.w * s);
  dst[threadIdx.x] = o;
}

// cast all three expert weight tensors fp32->bf16
__global__ __launch_bounds__(256) void k_cast(const float4* __restrict__ a,
                                              const float4* __restrict__ b,
                                              const float4* __restrict__ c,
                                              ushort4* __restrict__ oa,
                                              ushort4* __restrict__ ob,
                                              ushort4* __restrict__ oc) {
  int i = blockIdx.x * 256 + threadIdx.x;
  float4 v; ushort4 r;
  v = a[i]; r.x = f2bf(v.x); r.y = f2bf(v.y); r.z = f2bf(v.z); r.w = f2bf(v.w); oa[i] = r;
  v = b[i]; r.x = f2bf(v.x); r.y = f2bf(v.y); r.z = f2bf(v.z); r.w = f2bf(v.w); ob[i] = r;
  v = c[i]; r.x = f2bf(v.x); r.y = f2bf(v.y); r.z = f2bf(v.z); r.w = f2bf(v.w); oc[i] = r;
}

// ---------------- fused gate+up GEMM -> h = u * silu(g) ----------------
// BM=128 x BN=128 dual-acc tile; 1 block/CU; expert pinned to XCD (e = blockIdx&7).
// Stream = A x4 + B x8 = 201 MB (was 268).
__global__ __launch_bounds__(256, 1) void k_gemm_gu(const ushort* __restrict__ xs,
                                                    const ushort* __restrict__ wg,
                                                    const ushort* __restrict__ wu,
                                                    const int* __restrict__ cnt,
                                                    ushort* __restrict__ h) {
  __shared__ __align__(16) ushort As[BM * BK];      // 16 KB
  __shared__ __align__(16) ushort Bg[GU_BN * BK];   // 16 KB
  __shared__ __align__(16) ushort Bu[GU_BN * BK];   // 16 KB

  int tid = threadIdx.x;
  int wv = tid >> 6, lane = tid & 63;
  int wm = wv >> 1, wn = wv & 1;
  int frow = lane & 15, khalf = lane >> 4;

  int e = blockIdx.x & 7;
  int cnte = cnt[e];
  int off = 0;
#pragma unroll
  for (int i = 0; i < NE; i++) off += (i < e) ? cnt[i] : 0;
  const ushort* wgE = wg + (size_t)e * ID * HD;
  const ushort* wuE = wu + (size_t)e * ID * HD;

  for (int idl = blockIdx.x >> 3; idl < GU_SPACE; idl += GU_BPE) {
    int mt = idl >> 2;
    int nt = idl & 3;
    if (mt * BM >= cnte) break;
    int m0 = off + mt * BM;
    int rv = cnte - mt * BM; if (rv > BM) rv = BM;
    int n0 = nt * GU_BN;

    const ushort* aBase = xs + (size_t)m0 * HD;
    const ushort* gBase = wgE + (size_t)n0 * HD;
    const ushort* uBase = wuE + (size_t)n0 * HD;

    f32x4 accg[4][4] = {};
    f32x4 accu[4][4] = {};

    for (int k0 = 0; k0 < HD; k0 += BK) {
      __syncthreads();
      // A: 16 chunks, Bg: 16, Bu: 16 -> 12 glds per wave
#pragma unroll
      for (int i = 0; i < 4; i++) {
        int ci = wv * 4 + i;
        stageChunk(aBase + (size_t)(ci * 8) * HD, HD, k0, &As[ci * 8 * BK], lane);
        stageChunk(gBase + (size_t)(ci * 8) * HD, HD, k0, &Bg[ci * 8 * BK], lane);
        stageChunk(uBase + (size_t)(ci * 8) * HD, HD, k0, &Bu[ci * 8 * BK], lane);
      }
      __syncthreads();
#pragma unroll
      for (int s = 0; s < 2; s++) {
        int g = s * 4 + khalf;
        short8 af[4], bg[4], bu[4];
#pragma unroll
        for (int i = 0; i < 4; i++) af[i] = fragRd(As, wm * 64 + i * 16 + frow, g);
#pragma unroll
        for (int j = 0; j < 4; j++) {
          bg[j] = fragRd(Bg, wn * 64 + j * 16 + frow, g);
          bu[j] = fragRd(Bu, wn * 64 + j * 16 + frow, g);
        }
#pragma unroll
        for (int i = 0; i < 4; i++)
#pragma unroll
          for (int j = 0; j < 4; j++) {
            accg[i][j] = __builtin_amdgcn_mfma_f32_16x16x32_bf16(af[i], bg[j], accg[i][j], 0, 0, 0);
            accu[i][j] = __builtin_amdgcn_mfma_f32_16x16x32_bf16(af[i], bu[j], accu[i][j], 0, 0, 0);
          }
      }
    }

    int rb = wm * 64 + khalf * 4;
    int cb = n0 + wn * 64 + frow;
#pragma unroll
    for (int i = 0; i < 4; i++)
#pragma unroll
      for (int r = 0; r < 4; r++) {
        int m = rb + i * 16 + r;
        if (m < rv) {
          ushort* hrow = h + (size_t)(m0 + m) * ID + cb;
#pragma unroll
          for (int j = 0; j < 4; j++) {
            float g = accg[i][j][r], u = accu[i][j][r];
            float hv = u * g / (1.0f + __expf(-g));
            hrow[j * 16] = f2bf(hv);
          }
        }
      }
  }
}

// ---------------- down GEMM with row scatter ----------------
// BM=128 x BN=256 tile; stream = A x4 + B x8 = 100 MB (was 201).
__global__ __launch_bounds__(256, 1) void k_gemm_dn(const ushort* __restrict__ h,
                                                    const ushort* __restrict__ wd,
                                                    const int* __restrict__ cnt,
                                                    const int* __restrict__ perm,
                                                    float* __restrict__ out) {
  __shared__ __align__(16) ushort As[BM * BK];      // 16 KB
  __shared__ __align__(16) ushort Bs[DN_BN * BK];   // 32 KB

  int tid = threadIdx.x;
  int wv = tid >> 6, lane = tid & 63;
  int wm = wv >> 1, wn = wv & 1;
  int frow = lane & 15, khalf = lane >> 4;

  int e = blockIdx.x & 7;
  int cnte = cnt[e];
  int off = 0;
#pragma unroll
  for (int i = 0; i < NE; i++) off += (i < e) ? cnt[i] : 0;
  const ushort* wdE = wd + (size_t)e * HD * ID;

  for (int idl = blockIdx.x >> 3; idl < DN_SPACE; idl += DN_BPE) {
    int mt = idl >> 2;
    int nt = idl & 3;
    if (mt * BM >= cnte) break;
    int m0 = off + mt * BM;
    int rv = cnte - mt * BM; if (rv > BM) rv = BM;
    int n0 = nt * DN_BN;

    const ushort* aBase = h + (size_t)m0 * ID;
    const ushort* bBase = wdE + (size_t)n0 * ID;

    f32x4 acc[4][8] = {};

    for (int k0 = 0; k0 < ID; k0 += BK) {
      __syncthreads();
      // A: 16 chunks (4/wave), B: 32 chunks (8/wave)
#pragma unroll
      for (int i = 0; i < 4; i++) {
        int ci = wv * 4 + i;
        stageChunk(aBase + (size_t)(ci * 8) * ID, ID, k0, &As[ci * 8 * BK], lane);
      }
#pragma unroll
      for (int i = 0; i < 8; i++) {
        int ci = wv * 8 + i;
        stageChunk(bBase + (size_t)(ci * 8) * ID, ID, k0, &Bs[ci * 8 * BK], lane);
      }
      __syncthreads();
#pragma unroll
      for (int s = 0; s < 2; s++) {
        int g = s * 4 + khalf;
        short8 af[4], bf[8];
#pragma unroll
        for (int i = 0; i < 4; i++) af[i] = fragRd(As, wm * 64 + i * 16 + frow, g);
#pragma unroll
        for (int j = 0; j < 8; j++) bf[j] = fragRd(Bs, wn * 128 + j * 16 + frow, g);
#pragma unroll
        for (int i = 0; i < 4; i++)
#pragma unroll
          for (int j = 0; j < 8; j++)
            acc[i][j] = __builtin_amdgcn_mfma_f32_16x16x32_bf16(af[i], bf[j], acc[i][j], 0, 0, 0);
      }
    }

    int rb = wm * 64 + khalf * 4;
    int cb = n0 + wn * 128 + frow;
#pragma unroll
    for (int i = 0; i < 4; i++)
#pragma unroll
      for (int r = 0; r < 4; r++) {
        int m = rb + i * 16 + r;
        if (m < rv) {
          int t = perm[m0 + m];
          float* orow = out + (size_t)t * HD + cb;
#pragma unroll
          for (int j = 0; j < 8; j++) orow[j * 16] = acc[i][j][r];
        }
      }
  }
}

extern "C" void kernel_launch(void* const* d_in, const int* in_sizes, int n_in,
                              void* d_out, int out_size, void* d_ws, size_t ws_size,
                              hipStream_t stream) {
  const float* x     = (const float*)d_in[0];
  const float* gw    = (const float*)d_in[1];
  const float* wgate = (const float*)d_in[2];
  const float* wup   = (const float*)d_in[3];
  const float* wdown = (const float*)d_in[4];
  float* out = (float*)d_out;

  uint8_t* ws = (uint8_t*)d_ws;
  int*   cnt  = (int*)ws;                    // 8 ints
  int*   sel  = (int*)(ws + 256);
  int*   rank = sel + T_TOK;                 // unused (layout kept)
  int*   perm = rank + T_TOK;
  float* rw   = (float*)(perm + T_TOK);
  size_t o = 256 + (size_t)4 * 4 * T_TOK;
  ushort* wg_b = (ushort*)(ws + o); o += (size_t)NE * ID * HD * 2;
  ushort* wu_b = (ushort*)(ws + o); o += (size_t)NE * ID * HD * 2;
  ushort* wd_b = (ushort*)(ws + o); o += (size_t)NE * HD * ID * 2;
  ushort* xs   = (ushort*)(ws + o); o += (size_t)(T_TOK + BM) * HD * 2;
  ushort* hbuf = (ushort*)(ws + o); o += (size_t)(T_TOK + BM) * ID * 2;

  k_router<<<T_TOK / 4, 256, 0, stream>>>(x, gw, sel, rw);
  k_scan<<<1, 1024, 0, stream>>>(sel, cnt, perm);
  k_gather<<<T_TOK, 256, 0, stream>>>(x, rw, perm, xs);
  k_cast<<<(NE * ID * HD / 4) / 256, 256, 0, stream>>>(
      (const float4*)wgate, (const float4*)wup, (const float4*)wdown,
      (ushort4*)wg_b, (ushort4*)wu_b, (ushort4*)wd_b);
  k_gemm_gu<<<GU_GRID, 256, 0, stream>>>(xs, wg_b, wu_b, cnt, hbuf);
  k_gemm_dn<<<DN_GRID, 256, 0, stream>>>(hbuf, wd_b, cnt, perm, out);
}

// Round 7
// 215.715 us; speedup vs baseline: 1.1516x; 1.1516x over previous
//
#include <hip/hip_runtime.h>
#include <hip/hip_bf16.h>
#include <cstdint>
#include <cmath>

#define T_TOK 8192
#define HD 1024
#define ID 512
#define NE 8
#define BM 128
#define BK 64
#define MAXMT (T_TOK / BM)   // 64

#define GU_BN 64
#define GU_SPACE (MAXMT * (ID / GU_BN))   // 512; active ~64-72/expert
#define GU_BPE 64
#define GU_GRID (NE * GU_BPE)             // 512 -> 2 blocks/CU
#define DN_BN 128
#define DN_SPACE (MAXMT * (HD / DN_BN))   // 512; active ~64-72/expert
#define DN_BPE 64
#define DN_GRID (NE * DN_BPE)             // 512 -> 2 blocks/CU

#define CAST_BLOCKS ((NE * ID * HD / 4) / 256)   // 4096

typedef __attribute__((ext_vector_type(8))) short short8;
typedef __attribute__((ext_vector_type(4))) float f32x4;

__device__ __forceinline__ unsigned short f2bf(float f) {
  union { float f; unsigned int u; } v; v.f = f;
  unsigned int u = v.u;
  u += 0x7fffu + ((u >> 16) & 1u);   // RNE
  return (unsigned short)(u >> 16);
}

#if __has_builtin(__builtin_amdgcn_global_load_lds)
#define HAVE_GLDS 1
#endif

// Global->LDS 16B/lane. LDS dest = wave-uniform base + lane*16.
__device__ __forceinline__ void stage16(const ushort* __restrict__ g,
                                        ushort* lds_wave_base, int lane) {
#ifdef HAVE_GLDS
  __builtin_amdgcn_global_load_lds((const __attribute__((address_space(1))) void*)g,
                                   (__attribute__((address_space(3))) void*)lds_wave_base,
                                   16, 0, 0);
#else
  *(uint4*)(lds_wave_base + (size_t)lane * 8) = *(const uint4*)g;
#endif
}

// BK=64: one glds instr stages 8 rows x 128B. Lane l -> row rl=l>>3, dest slot c=l&7.
// Slot c holds global colgroup c ^ (rl&7) (XOR swizzle; verified 0 bank conflicts).
__device__ __forceinline__ void stageChunk(const ushort* __restrict__ rowbase, size_t ld,
                                           int k0, ushort* ldsChunk, int lane) {
  int rl = lane >> 3;
  int gc = (lane & 7) ^ (rl & 7);
  stage16(rowbase + (size_t)rl * ld + k0 + gc * 8, ldsChunk, lane);
}

// Read 8-elem bf16 frag at (row r, global colgroup g), undoing swizzle.
__device__ __forceinline__ short8 fragRd(const ushort* buf, int r, int g) {
  int slot = g ^ (r & 7);
  return *(const short8*)&buf[r * BK + slot * 8];
}

// ---------------- router: logits (fp64 acc), argmax, sigmoid ----------------
__global__ __launch_bounds__(256) void k_router(const float* __restrict__ x,
                                                const float* __restrict__ gw,
                                                int* __restrict__ sel,
                                                float* __restrict__ rw) {
  int wv = threadIdx.x >> 6, lane = threadIdx.x & 63;
  int t = blockIdx.x * 4 + wv;
  const float4* xr = (const float4*)(x + (size_t)t * HD);
  double acc[NE];
#pragma unroll
  for (int e = 0; e < NE; e++) acc[e] = 0.0;
#pragma unroll
  for (int j = 0; j < 4; j++) {
    float4 xv = xr[lane + 64 * j];
#pragma unroll
    for (int e = 0; e < NE; e++) {
      float4 wv4 = ((const float4*)(gw + e * HD))[lane + 64 * j];
      acc[e] += (double)xv.x * wv4.x + (double)xv.y * wv4.y +
                (double)xv.z * wv4.z + (double)xv.w * wv4.w;
    }
  }
#pragma unroll
  for (int e = 0; e < NE; e++)
    for (int off = 32; off >= 1; off >>= 1)
      acc[e] += __shfl_xor(acc[e], off);
  if (lane == 0) {
    double best = acc[0]; int bi = 0;
#pragma unroll
    for (int e = 1; e < NE; e++) if (acc[e] > best) { best = acc[e]; bi = e; }
    sel[t] = bi;
    rw[t] = (float)(1.0 / (1.0 + exp(-best)));
  }
}

// ---------------- single-block count + scan + permutation (no atomics) ----------
__global__ __launch_bounds__(1024) void k_scan(const int* __restrict__ sel,
                                               int* __restrict__ cnt,
                                               int* __restrict__ perm) {
  __shared__ int wbase[NE][16];
  __shared__ int off[NE];
  int tid = threadIdx.x;
  int wv = tid >> 6, lane = tid & 63;

  int4 s0 = ((const int4*)sel)[tid * 2];
  int4 s1 = ((const int4*)sel)[tid * 2 + 1];
  int sl[8] = {s0.x, s0.y, s0.z, s0.w, s1.x, s1.y, s1.z, s1.w};

  int c[NE];
#pragma unroll
  for (int e = 0; e < NE; e++) c[e] = 0;
#pragma unroll
  for (int i = 0; i < 8; i++)
#pragma unroll
    for (int e = 0; e < NE; e++) c[e] += (sl[i] == e) ? 1 : 0;

  int pre[NE];
#pragma unroll
  for (int e = 0; e < NE; e++) {
    int v = c[e];
#pragma unroll
    for (int d = 1; d < 64; d <<= 1) {
      int u = __shfl_up(v, d);
      if (lane >= d) v += u;
    }
    pre[e] = v - c[e];
    if (lane == 63) wbase[e][wv] = v;
  }
  __syncthreads();
  if (tid < NE) {
    int a = 0;
#pragma unroll
    for (int w = 0; w < 16; w++) { int v = wbase[tid][w]; wbase[tid][w] = a; a += v; }
    cnt[tid] = a;
    off[tid] = a;
  }
  __syncthreads();
  if (tid == 0) {
    int a = 0;
#pragma unroll
    for (int e = 0; e < NE; e++) { int v = off[e]; off[e] = a; a += v; }
  }
  __syncthreads();
  int t0 = tid * 8;
#pragma unroll
  for (int i = 0; i < 8; i++) {
    int e = sl[i];
    int r = 0;
#pragma unroll
    for (int q = 0; q < NE; q++)
      if (q == e) { r = off[q] + wbase[q][wv] + pre[q]; pre[q]++; }
    perm[r] = t0 + i;
  }
}

// ---------------- prep: gather (blocks 0..8191) + weight cast (rest) ----------
__global__ __launch_bounds__(256) void k_prep(const float* __restrict__ x,
                                              const float* __restrict__ rw,
                                              const int* __restrict__ perm,
                                              ushort* __restrict__ xs,
                                              const float4* __restrict__ wgate,
                                              const float4* __restrict__ wup,
                                              const float4* __restrict__ wdown,
                                              ushort4* __restrict__ wg_b,
                                              ushort4* __restrict__ wu_b,
                                              ushort4* __restrict__ wd_b) {
  int b = blockIdx.x;
  if (b < T_TOK) {
    int t = perm[b];
    float s = rw[t];
    const float4* src = (const float4*)(x + (size_t)t * HD);
    ushort4* dst = (ushort4*)(xs + (size_t)b * HD);
    float4 v = src[threadIdx.x];
    ushort4 o;
    o.x = f2bf(v.x * s); o.y = f2bf(v.y * s); o.z = f2bf(v.z * s); o.w = f2bf(v.w * s);
    dst[threadIdx.x] = o;
  } else {
    int i = (b - T_TOK) * 256 + threadIdx.x;
    float4 v; ushort4 r;
    v = wgate[i]; r.x = f2bf(v.x); r.y = f2bf(v.y); r.z = f2bf(v.z); r.w = f2bf(v.w); wg_b[i] = r;
    v = wup[i];   r.x = f2bf(v.x); r.y = f2bf(v.y); r.z = f2bf(v.z); r.w = f2bf(v.w); wu_b[i] = r;
    v = wdown[i]; r.x = f2bf(v.x); r.y = f2bf(v.y); r.z = f2bf(v.z); r.w = f2bf(v.w); wd_b[i] = r;
  }
}

// ---------------- fused gate+up GEMM -> h = u * silu(g) (R5 config) ----------
// BM=128 x BN=64, BK=64, expert pinned to XCD (e = blockIdx&7), 2 blocks/CU.
__global__ __launch_bounds__(256, 2) void k_gemm_gu(const ushort* __restrict__ xs,
                                                    const ushort* __restrict__ wg,
                                                    const ushort* __restrict__ wu,
                                                    const int* __restrict__ cnt,
                                                    ushort* __restrict__ h) {
  __shared__ __align__(16) ushort As[BM * BK];      // 16 KB
  __shared__ __align__(16) ushort Bg[GU_BN * BK];   // 8 KB
  __shared__ __align__(16) ushort Bu[GU_BN * BK];   // 8 KB

  int tid = threadIdx.x;
  int wv = tid >> 6, lane = tid & 63;
  int wm = wv >> 1, wn = wv & 1;
  int frow = lane & 15, khalf = lane >> 4;

  int e = blockIdx.x & 7;
  int cnte = cnt[e];
  int off = 0;
#pragma unroll
  for (int i = 0; i < NE; i++) off += (i < e) ? cnt[i] : 0;
  const ushort* wgE = wg + (size_t)e * ID * HD;
  const ushort* wuE = wu + (size_t)e * ID * HD;

  for (int idl = blockIdx.x >> 3; idl < GU_SPACE; idl += GU_BPE) {
    int mt = idl >> 3;
    int nt = idl & 7;
    if (mt * BM >= cnte) break;
    int m0 = off + mt * BM;
    int rv = cnte - mt * BM; if (rv > BM) rv = BM;
    int n0 = nt * GU_BN;

    const ushort* aBase = xs + (size_t)m0 * HD;
    const ushort* gBase = wgE + (size_t)n0 * HD;
    const ushort* uBase = wuE + (size_t)n0 * HD;

    f32x4 accg[4][2] = {};
    f32x4 accu[4][2] = {};

    for (int k0 = 0; k0 < HD; k0 += BK) {
      __syncthreads();
#pragma unroll
      for (int i = 0; i < 4; i++) {
        int ci = wv * 4 + i;
        stageChunk(aBase + (size_t)(ci * 8) * HD, HD, k0, &As[ci * 8 * BK], lane);
      }
#pragma unroll
      for (int i = 0; i < 2; i++) {
        int ci = wv * 2 + i;
        stageChunk(gBase + (size_t)(ci * 8) * HD, HD, k0, &Bg[ci * 8 * BK], lane);
        stageChunk(uBase + (size_t)(ci * 8) * HD, HD, k0, &Bu[ci * 8 * BK], lane);
      }
      __syncthreads();
      short8 af[2][4], bg[2][2], bu[2][2];
#pragma unroll
      for (int s = 0; s < 2; s++) {
        int g = s * 4 + khalf;
#pragma unroll
        for (int i = 0; i < 4; i++) af[s][i] = fragRd(As, wm * 64 + i * 16 + frow, g);
#pragma unroll
        for (int j = 0; j < 2; j++) {
          bg[s][j] = fragRd(Bg, wn * 32 + j * 16 + frow, g);
          bu[s][j] = fragRd(Bu, wn * 32 + j * 16 + frow, g);
        }
      }
#pragma unroll
      for (int s = 0; s < 2; s++)
#pragma unroll
        for (int i = 0; i < 4; i++)
#pragma unroll
          for (int j = 0; j < 2; j++) {
            accg[i][j] = __builtin_amdgcn_mfma_f32_16x16x32_bf16(af[s][i], bg[s][j], accg[i][j], 0, 0, 0);
            accu[i][j] = __builtin_amdgcn_mfma_f32_16x16x32_bf16(af[s][i], bu[s][j], accu[i][j], 0, 0, 0);
          }
    }

    int rb = wm * 64 + khalf * 4;
    int cb = n0 + wn * 32 + frow;
#pragma unroll
    for (int i = 0; i < 4; i++)
#pragma unroll
      for (int r = 0; r < 4; r++) {
        int m = rb + i * 16 + r;
        if (m < rv) {
          ushort* hrow = h + (size_t)(m0 + m) * ID + cb;
#pragma unroll
          for (int j = 0; j < 2; j++) {
            float g = accg[i][j][r], u = accu[i][j][r];
            float hv = u * g / (1.0f + __expf(-g));
            hrow[j * 16] = f2bf(hv);
          }
        }
      }
  }
}

// ---------------- down GEMM with row scatter ----------------
// BM=128 x BN=128, grid 512 (2 blocks/CU): stream = A x8 + B x8 = 128 MB (was 192).
__global__ __launch_bounds__(256, 2) void k_gemm_dn(const ushort* __restrict__ h,
                                                    const ushort* __restrict__ wd,
                                                    const int* __restrict__ cnt,
                                                    const int* __restrict__ perm,
                                                    float* __restrict__ out) {
  __shared__ __align__(16) ushort As[BM * BK];      // 16 KB
  __shared__ __align__(16) ushort Bs[DN_BN * BK];   // 16 KB

  int tid = threadIdx.x;
  int wv = tid >> 6, lane = tid & 63;
  int wm = wv >> 1, wn = wv & 1;
  int frow = lane & 15, khalf = lane >> 4;

  int e = blockIdx.x & 7;
  int cnte = cnt[e];
  int off = 0;
#pragma unroll
  for (int i = 0; i < NE; i++) off += (i < e) ? cnt[i] : 0;
  const ushort* wdE = wd + (size_t)e * HD * ID;

  for (int idl = blockIdx.x >> 3; idl < DN_SPACE; idl += DN_BPE) {
    int mt = idl >> 3;
    int nt = idl & 7;
    if (mt * BM >= cnte) break;
    int m0 = off + mt * BM;
    int rv = cnte - mt * BM; if (rv > BM) rv = BM;
    int n0 = nt * DN_BN;

    const ushort* aBase = h + (size_t)m0 * ID;
    const ushort* bBase = wdE + (size_t)n0 * ID;

    f32x4 acc[4][4] = {};

    for (int k0 = 0; k0 < ID; k0 += BK) {
      __syncthreads();
#pragma unroll
      for (int i = 0; i < 4; i++) {
        int ci = wv * 4 + i;
        stageChunk(aBase + (size_t)(ci * 8) * ID, ID, k0, &As[ci * 8 * BK], lane);
        stageChunk(bBase + (size_t)(ci * 8) * ID, ID, k0, &Bs[ci * 8 * BK], lane);
      }
      __syncthreads();
#pragma unroll
      for (int s = 0; s < 2; s++) {
        int g = s * 4 + khalf;
        short8 af[4], bf[4];
#pragma unroll
        for (int i = 0; i < 4; i++) af[i] = fragRd(As, wm * 64 + i * 16 + frow, g);
#pragma unroll
        for (int j = 0; j < 4; j++) bf[j] = fragRd(Bs, wn * 64 + j * 16 + frow, g);
#pragma unroll
        for (int i = 0; i < 4; i++)
#pragma unroll
          for (int j = 0; j < 4; j++)
            acc[i][j] = __builtin_amdgcn_mfma_f32_16x16x32_bf16(af[i], bf[j], acc[i][j], 0, 0, 0);
      }
    }

    int rb = wm * 64 + khalf * 4;
    int cb = n0 + wn * 64 + frow;
#pragma unroll
    for (int i = 0; i < 4; i++)
#pragma unroll
      for (int r = 0; r < 4; r++) {
        int m = rb + i * 16 + r;
        if (m < rv) {
          int t = perm[m0 + m];
          float* orow = out + (size_t)t * HD + cb;
#pragma unroll
          for (int j = 0; j < 4; j++) orow[j * 16] = acc[i][j][r];
        }
      }
  }
}

extern "C" void kernel_launch(void* const* d_in, const int* in_sizes, int n_in,
                              void* d_out, int out_size, void* d_ws, size_t ws_size,
                              hipStream_t stream) {
  const float* x     = (const float*)d_in[0];
  const float* gw    = (const float*)d_in[1];
  const float* wgate = (const float*)d_in[2];
  const float* wup   = (const float*)d_in[3];
  const float* wdown = (const float*)d_in[4];
  float* out = (float*)d_out;

  uint8_t* ws = (uint8_t*)d_ws;
  int*   cnt  = (int*)ws;                    // 8 ints
  int*   sel  = (int*)(ws + 256);
  int*   rank = sel + T_TOK;                 // unused (layout kept)
  int*   perm = rank + T_TOK;
  float* rw   = (float*)(perm + T_TOK);
  size_t o = 256 + (size_t)4 * 4 * T_TOK;
  ushort* wg_b = (ushort*)(ws + o); o += (size_t)NE * ID * HD * 2;
  ushort* wu_b = (ushort*)(ws + o); o += (size_t)NE * ID * HD * 2;
  ushort* wd_b = (ushort*)(ws + o); o += (size_t)NE * HD * ID * 2;
  ushort* xs   = (ushort*)(ws + o); o += (size_t)(T_TOK + BM) * HD * 2;
  ushort* hbuf = (ushort*)(ws + o); o += (size_t)(T_TOK + BM) * ID * 2;

  k_router<<<T_TOK / 4, 256, 0, stream>>>(x, gw, sel, rw);
  k_scan<<<1, 1024, 0, stream>>>(sel, cnt, perm);
  k_prep<<<T_TOK + CAST_BLOCKS, 256, 0, stream>>>(
      x, rw, perm, xs,
      (const float4*)wgate, (const float4*)wup, (const float4*)wdown,
      (ushort4*)wg_b, (ushort4*)wu_b, (ushort4*)wd_b);
  k_gemm_gu<<<GU_GRID, 256, 0, stream>>>(xs, wg_b, wu_b, cnt, hbuf);
  k_gemm_dn<<<DN_GRID, 256, 0, stream>>>(hbuf, wd_b, cnt, perm, out);
}